// Round 6
// baseline (264.922 us; speedup 1.0000x reference)
//
#include <hip/hip_runtime.h>
#include <math.h>

#define NTOK   16384
#define DDIM   2048
#define EDIM   128
#define HDIM   128
#define TOKT   32
#define KC     32
#define NCH    (DDIM / KC)   // 64 chunks of 32 k

typedef __attribute__((ext_vector_type(8))) _Float16 half8;
typedef __attribute__((ext_vector_type(4))) _Float16 half4;
typedef __attribute__((ext_vector_type(4))) float    f32x4;

// b32-granule XOR swizzle for epilogue A[32][128]: conflict-free row+column.
__device__ __forceinline__ int swz(int t, int e) {
  return t * EDIM + ((e & 96) | ((e ^ t) & 31));
}

// ---- W pre-convert: fragment-ordered f16 hi/lo planes in workspace ----
// frag idx -> (nt, ks, lane); lane holds B[k=ks*32+(lane>>4)*8+j][n=nt*16+(lane&15)]
// = Wr[n][k], scaled by 32 (hi) and 32*2048 (lo) to dodge f16 denormals.
__global__ __launch_bounds__(256)
void conv_w(const float* __restrict__ Wr,
            _Float16* __restrict__ wh, _Float16* __restrict__ wl) {
  const int idx  = (int)blockIdx.x * 256 + (int)threadIdx.x;  // 0..32767
  const int lane = idx & 63;
  const int ks   = (idx >> 6) & 63;
  const int nt   = idx >> 12;
  const int n    = nt * 16 + (lane & 15);
  const int k0   = ks * 32 + (lane >> 4) * 8;
  half8 h, l;
#pragma unroll
  for (int j = 0; j < 8; ++j) {
    const float w = Wr[(size_t)n * DDIM + k0 + j] * 32.0f;
    const _Float16 hh = (_Float16)w;
    h[j] = hh;
    l[j] = (_Float16)((w - (float)hh) * 2048.0f);
  }
  *(half8*)(wh + (size_t)idx * 8) = h;
  *(half8*)(wl + (size_t)idx * 8) = l;
}

__global__ __launch_bounds__(512, 4)     // 4 waves/EU -> 2 blocks/CU
void fused_router(const float* __restrict__ x,
                  const _Float16* __restrict__ wsh,
                  const _Float16* __restrict__ wsl,
                  const float* __restrict__ Wd,
                  const float* __restrict__ gamma,
                  const float* __restrict__ beta,
                  const float* __restrict__ rnn,
                  const float* __restrict__ gum,
                  float* __restrict__ outb,
                  float* __restrict__ outa) {
  // GEMM phase: xs halves, buf b at b*2048; hi plane [32t][32k] at +0, lo at +1024.
  // Epilogue: A = bytes [0,16K) (32x128 swz), G4 = bytes [16K,32K) (f4-swz).
  __shared__ char smraw[32768];
  _Float16* const xs = (_Float16*)smraw;
  float* const A  = (float*)smraw;
  float* const G4 = (float*)(smraw + 16384);

  const int tid  = (int)threadIdx.x;
  const int wv   = __builtin_amdgcn_readfirstlane(tid >> 6);  // 0..7
  const int lane = tid & 63;
  const int t0   = (int)blockIdx.x * TOKT;

  // MFMA mapping: wave = both m-tiles (32 tok) x 1 n-tile, full K per wave.
  const int nt   = wv;                   // 0..7
  const int quad = lane >> 4;
  const int col  = lane & 15;

  const int offA0 = col * 32 + quad * 8;          // mt0 rows, halves (+buf*2048)
  const int offA1 = (16 + col) * 32 + quad * 8;   // mt1 rows  (lo plane: +1024)

  // x staging: threads 0..255 -> (token, 4 consecutive k)
  const bool xstage = tid < 256;
  const int  sx_t   = tid >> 3;          // 0..31
  const int  sx_k   = (tid & 7) * 4;     // 0..28
  const float* xg   = x + (size_t)(t0 + sx_t) * DDIM + sx_k;
  const int  sx_off = sx_t * 32 + sx_k;  // halves within hi plane

  // B-fragment global pointers (per-chunk stride 512 halves)
  const _Float16* whg = wsh + (size_t)nt * 32768 + (size_t)lane * 8;
  const _Float16* wlg = wsl + (size_t)nt * 32768 + (size_t)lane * 8;

  f32x4 hh0 = {0,0,0,0}, cr0 = {0,0,0,0}, hh1 = {0,0,0,0}, cr1 = {0,0,0,0};

  // ---- preamble: stage x chunk 0 into buf 0; preload B chunk 0 ----
  if (xstage) {
    const float4 v4 = *(const float4*)xg;
    half4 h, l;
#pragma unroll
    for (int m = 0; m < 4; ++m) {
      const float v = (&v4.x)[m];
      const _Float16 hv = (_Float16)v;
      h[m] = hv; l[m] = (_Float16)((v - (float)hv) * 2048.0f);
    }
    *(half4*)&xs[sx_off] = h;
    *(half4*)&xs[1024 + sx_off] = l;
  }
  half8 bh = *(const half8*)whg;
  half8 bl = *(const half8*)wlg;

  for (int c = 0; c < NCH; ++c) {
    __syncthreads();                     // buf (c&1) visible; buf (c&1)^1 free
    half8 nbh = bh, nbl = bl; float4 npx;
    if (c + 1 < NCH) {                   // prefetch next B (regs) + next x
      nbh = *(const half8*)(whg + (size_t)(c + 1) * 512);
      nbl = *(const half8*)(wlg + (size_t)(c + 1) * 512);
      if (xstage) npx = *(const float4*)(xg + (c + 1) * KC);
    }
    const int bo = (c & 1) * 2048;
    const half8 ah0 = *(const half8*)&xs[bo + offA0];
    const half8 al0 = *(const half8*)&xs[bo + 1024 + offA0];
    const half8 ah1 = *(const half8*)&xs[bo + offA1];
    const half8 al1 = *(const half8*)&xs[bo + 1024 + offA1];

    hh0 = __builtin_amdgcn_mfma_f32_16x16x32_f16(ah0, bh, hh0, 0, 0, 0);
    cr0 = __builtin_amdgcn_mfma_f32_16x16x32_f16(ah0, bl, cr0, 0, 0, 0);
    cr0 = __builtin_amdgcn_mfma_f32_16x16x32_f16(al0, bh, cr0, 0, 0, 0);
    hh1 = __builtin_amdgcn_mfma_f32_16x16x32_f16(ah1, bh, hh1, 0, 0, 0);
    cr1 = __builtin_amdgcn_mfma_f32_16x16x32_f16(ah1, bl, cr1, 0, 0, 0);
    cr1 = __builtin_amdgcn_mfma_f32_16x16x32_f16(al1, bh, cr1, 0, 0, 0);

    if (c + 1 < NCH && xstage) {         // convert + write into the free buffer
      const int bn = ((c + 1) & 1) * 2048;
      half4 h, l;
#pragma unroll
      for (int m = 0; m < 4; ++m) {
        const float v = (&npx.x)[m];
        const _Float16 hv = (_Float16)v;
        h[m] = hv; l[m] = (_Float16)((v - (float)hv) * 2048.0f);
      }
      *(half4*)&xs[bn + sx_off] = h;
      *(half4*)&xs[bn + 1024 + sx_off] = l;
    }
    bh = nbh; bl = nbl;
  }
  __syncthreads();                       // GEMM LDS dead

  // ---- unscale, add rnn, write emb to A (C/D: col=lane&15, row=quad*4+r) ----
  {
    const int e  = nt * 16 + col;
    const float rv = rnn[e];
#pragma unroll
    for (int r = 0; r < 4; ++r) {
      A[swz(quad * 4 + r, e)] =
          hh0[r] * (1.0f / 32.0f) + cr0[r] * (1.0f / 65536.0f) + rv;
      A[swz(16 + quad * 4 + r, e)] =
          hh1[r] * (1.0f / 32.0f) + cr1[r] * (1.0f / 65536.0f) + rv;
    }
  }
  __syncthreads();

  // ---- LayerNorm + exact GELU: 4 tokens per wave; G -> G4 (float4-swizzled) ----
  {
    const float gm0 = gamma[lane], gm1 = gamma[lane + 64];
    const float bt0 = beta[lane],  bt1 = beta[lane + 64];
    for (int tt = wv * 4; tt < wv * 4 + 4; ++tt) {
      const float v0 = A[swz(tt, lane)];
      const float v1 = A[swz(tt, lane + 64)];
      float s = v0 + v1;
#pragma unroll
      for (int m = 32; m; m >>= 1) s += __shfl_xor(s, m);
      const float mu = s * (1.0f / 128.0f);
      const float d0 = v0 - mu, d1 = v1 - mu;
      float q = d0 * d0 + d1 * d1;
#pragma unroll
      for (int m = 32; m; m >>= 1) q += __shfl_xor(q, m);
      const float rstd = 1.0f / sqrtf(q * (1.0f / 128.0f) + 1e-5f);
      const float h0v = d0 * rstd * gm0 + bt0;
      const float h1v = d1 * rstd * gm1 + bt1;
      const float g0 = 0.5f * h0v * (1.0f + erff(h0v * 0.70710678118654752f));
      const float g1 = 0.5f * h1v * (1.0f + erff(h1v * 0.70710678118654752f));
      const int e0a = lane, e1a = lane + 64;
      G4[(tt * 32 + (((e0a >> 2) ^ (tt & 31)))) * 4 + (e0a & 3)] = g0;
      G4[(tt * 32 + (((e1a >> 2) ^ (tt & 31)))) * 4 + (e1a & 3)] = g1;
    }
  }
  __syncthreads();

  // ---- decoder GEMM: wave = 8 h-rows x 32 tokens, two h-halves ----
  // lane = token (low 5 bits); both lane-halves duplicate work (same writes).
  {
    const int tok = lane & 31;
#pragma unroll
    for (int hb = 0; hb < 2; ++hb) {
      const int e0h = hb * 64 + wv * 8;
      float acc2[8];
#pragma unroll
      for (int j = 0; j < 8; ++j) acc2[j] = 0.0f;
      const float4* wd4 = (const float4*)(Wd + (size_t)e0h * EDIM);  // uniform
#pragma unroll 2
      for (int kg = 0; kg < EDIM / 4; ++kg) {
        const float4 gv = *(const float4*)&G4[(tok * 32 + (kg ^ tok)) * 4];
#pragma unroll
        for (int j = 0; j < 8; ++j) {
          const float4 w = wd4[(size_t)j * (EDIM / 4) + kg];
          acc2[j] = fmaf(gv.x, w.x,
                    fmaf(gv.y, w.y,
                    fmaf(gv.z, w.z,
                    fmaf(gv.w, w.w, acc2[j]))));
        }
      }
      if (lane < 32) {
#pragma unroll
        for (int j = 0; j < 8; ++j) A[swz(tok, e0h + j)] = acc2[j];
      }
    }
  }
  __syncthreads();

  // ---- gumbel-sigmoid, exact top-k (value then lower-index), output ----
  for (int tt = wv * 4; tt < wv * 4 + 4; ++tt) {
    const size_t T = (size_t)(t0 + tt);
    const float l0 = A[swz(tt, lane)];
    const float l1 = A[swz(tt, lane + 64)];
    const float gn0 = gum[T * HDIM + lane];
    const float gn1 = gum[T * HDIM + lane + 64];
    const float z0 = (l0 + gn0 + 3.0f) * 2.5f;
    const float z1 = (l1 + gn1 + 3.0f) * 2.5f;
    const float ba0 = 1.0f / (1.0f + expf(-z0));
    const float ba1 = 1.0f / (1.0f + expf(-z1));
    const unsigned ub0 = __float_as_uint(ba0);   // ba in (0,1]: bits monotone
    const unsigned ub1 = __float_as_uint(ba1);
    const int r0 = ba0 > 0.5f;                   // round: 0.5 -> 0
    const int r1 = ba1 > 0.5f;
    const int cnt = __popcll(__ballot(r0)) + __popcll(__ballot(r1));
    float bin0, bin1;
    if (cnt > 32) {
      unsigned v = 0u;                            // radix-select 32nd largest
#pragma unroll
      for (int b = 29; b >= 0; --b) {
        const unsigned cand = v | (1u << b);
        const int cc = __popcll(__ballot(ub0 >= cand)) + __popcll(__ballot(ub1 >= cand));
        if (cc >= 32) v = cand;
      }
      const int cgt = __popcll(__ballot(ub0 > v)) + __popcll(__ballot(ub1 > v));
      const int r = 32 - cgt;                     // tied slots; lower index wins
      const unsigned long long t0b = __ballot(ub0 == v);
      const unsigned long long t1b = __ballot(ub1 == v);
      const int n0 = __popcll(t0b);
      const unsigned long long mlt = (1ull << lane) - 1ull;
      const int rk0 = __popcll(t0b & mlt);
      const int rk1 = n0 + __popcll(t1b & mlt);
      bin0 = (ub0 > v || (ub0 == v && rk0 < r)) ? 1.0f : 0.0f;
      bin1 = (ub1 > v || (ub1 == v && rk1 < r)) ? 1.0f : 0.0f;
    } else if (cnt == 0) {
      float m = fmaxf(ba0, ba1);
#pragma unroll
      for (int mm = 32; mm; mm >>= 1) m = fmaxf(m, __shfl_xor(m, mm));
      const unsigned long long e0b = __ballot(ba0 == m);
      const unsigned long long e1b = __ballot(ba1 == m);
      const int hstar = e0b ? (__ffsll((unsigned long long)e0b) - 1)
                            : (64 + __ffsll((unsigned long long)e1b) - 1);
      bin0 = (lane == hstar) ? 1.0f : 0.0f;
      bin1 = (lane + 64 == hstar) ? 1.0f : 0.0f;
    } else {
      bin0 = r0 ? 1.0f : 0.0f;
      bin1 = r1 ? 1.0f : 0.0f;
    }
    outb[T * HDIM + lane]      = bin0;
    outb[T * HDIM + lane + 64] = bin1;
    outa[T * HDIM + lane]      = ba0;
    outa[T * HDIM + lane + 64] = ba1;
  }
}

extern "C" void kernel_launch(void* const* d_in, const int* in_sizes, int n_in,
                              void* d_out, int out_size, void* d_ws, size_t ws_size,
                              hipStream_t stream) {
  (void)in_sizes; (void)n_in; (void)ws_size; (void)out_size;
  const float* x   = (const float*)d_in[0];
  const float* Wr  = (const float*)d_in[1];
  const float* Wd  = (const float*)d_in[2];
  const float* gm  = (const float*)d_in[3];
  const float* bt  = (const float*)d_in[4];
  const float* rnn = (const float*)d_in[5];
  const float* gum = (const float*)d_in[6];
  float* outb = (float*)d_out;
  float* outa = outb + (size_t)NTOK * HDIM;   // tuple: (binary, binary_approx)

  _Float16* wh = (_Float16*)d_ws;             // 512 KB
  _Float16* wl = wh + (size_t)EDIM * DDIM;    // 512 KB

  conv_w<<<dim3(128), dim3(256), 0, stream>>>(Wr, wh, wl);
  fused_router<<<dim3(NTOK / TOKT), dim3(512), 0, stream>>>(
      x, wh, wl, Wd, gm, bt, rnn, gum, outb, outa);
}

// Round 7
// 263.541 us; speedup vs baseline: 1.0052x; 1.0052x over previous
//
#include <hip/hip_runtime.h>
#include <math.h>

#define NTOK   16384
#define DDIM   2048
#define EDIM   128
#define HDIM   128
#define TOKT   32
#define KC     64
#define NCH    (DDIM / KC)   // 32 chunks of 64 k

typedef __attribute__((ext_vector_type(8))) _Float16 half8;
typedef __attribute__((ext_vector_type(4))) float    f32x4;

// b32-granule XOR swizzle for epilogue A[32][128]: conflict-free row+column.
__device__ __forceinline__ int swz(int t, int e) {
  return t * EDIM + ((e & 96) | ((e ^ t) & 31));
}

// ---- W pre-convert: fragment-ordered f16 hi/lo planes in workspace ----
// layout (halves): nt*32768 + ks*512 + lane*8 + j ; lane holds
// B[k=ks*32+(lane>>4)*8+j][n=nt*16+(lane&15)] = Wr[n][k], scaled by 32 (hi)
// and 32*2048 (lo) to dodge f16 denormals.
__global__ __launch_bounds__(256)
void conv_w(const float* __restrict__ Wr,
            _Float16* __restrict__ wh, _Float16* __restrict__ wl) {
  const int idx  = (int)blockIdx.x * 256 + (int)threadIdx.x;  // 0..32767
  const int lane = idx & 63;
  const int ks   = (idx >> 6) & 63;
  const int nt   = idx >> 12;
  const int n    = nt * 16 + (lane & 15);
  const int k0   = ks * 32 + (lane >> 4) * 8;
  half8 h, l;
#pragma unroll
  for (int j = 0; j < 8; ++j) {
    const float w = Wr[(size_t)n * DDIM + k0 + j] * 32.0f;
    const _Float16 hh = (_Float16)w;
    h[j] = hh;
    l[j] = (_Float16)((w - (float)hh) * 2048.0f);
  }
  *(half8*)(wh + (size_t)idx * 8) = h;
  *(half8*)(wl + (size_t)idx * 8) = l;
}

__global__ __launch_bounds__(512, 4)     // 4 waves/EU -> 2 blocks/CU
void fused_router(const float* __restrict__ x,
                  const _Float16* __restrict__ wsh,
                  const _Float16* __restrict__ wsl,
                  const float* __restrict__ Wd,
                  const float* __restrict__ gamma,
                  const float* __restrict__ beta,
                  const float* __restrict__ rnn,
                  const float* __restrict__ gum,
                  float* __restrict__ outb,
                  float* __restrict__ outa) {
  // GEMM phase (halves index space xs): buffer b at b*4096.
  //   hi plane: ks*1024 + tile*512 + lane*8 + j   (2048 halves)
  //   lo plane: +2048
  // Fragment-ordered: compute reads are lane*16 B contiguous (conflict-free);
  // staging writes hit 8 distinct banks per phase-group (conflict-free).
  // Epilogue: A = bytes [0,16K) (32x128 swz), G4 = bytes [16K,32K) (f4-swz).
  __shared__ char smraw[32768];
  _Float16* const xs = (_Float16*)smraw;
  float* const A  = (float*)smraw;
  float* const G4 = (float*)(smraw + 16384);

  const int tid  = (int)threadIdx.x;
  const int wv   = __builtin_amdgcn_readfirstlane(tid >> 6);  // 0..7
  const int lane = tid & 63;
  const int t0   = (int)blockIdx.x * TOKT;

  // MFMA mapping: wave = both m-tiles (32 tok) x 1 n-tile, full K per wave.
  const int nt   = wv;                   // 0..7
  const int quad = lane >> 4;
  const int col  = lane & 15;

  // A-frag read offsets (halves), + b*4096; lo: +2048
  const int offA00 = 0 * 1024 + 0 * 512 + lane * 8;   // ks0 tile0
  const int offA01 = 0 * 1024 + 1 * 512 + lane * 8;   // ks0 tile1
  const int offA10 = 1 * 1024 + 0 * 512 + lane * 8;   // ks1 tile0
  const int offA11 = 1 * 1024 + 1 * 512 + lane * 8;   // ks1 tile1

  // x staging: threads 0..255 -> (t, 8 consecutive k)
  const bool xstage = tid < 256;
  const int  sx_t   = ((tid >> 6) << 3) | (tid & 7);  // 0..31
  const int  sx_q   = (tid >> 3) & 7;                 // k-octet 0..7
  const float* xg   = x + (size_t)(t0 + sx_t) * DDIM + sx_q * 8;
  const int  sx_off = (sx_q >> 2) * 1024 + (sx_t >> 4) * 512 +
                      (((sx_q & 3) * 16 + (sx_t & 15)) * 8);  // hi; lo +2048

  // B-fragment global pointers (per-kstep stride 512 halves)
  const _Float16* whg = wsh + (size_t)nt * 32768 + (size_t)lane * 8;
  const _Float16* wlg = wsl + (size_t)nt * 32768 + (size_t)lane * 8;

  f32x4 hh0 = {0,0,0,0}, cr0 = {0,0,0,0}, hh1 = {0,0,0,0}, cr1 = {0,0,0,0};

  // ---- preamble: stage x chunk 0 into buf 0; preload B chunk 0 ----
  if (xstage) {
    const float4 v0 = *(const float4*)xg;
    const float4 v1 = *(const float4*)(xg + 4);
    half8 h, l;
#pragma unroll
    for (int m = 0; m < 4; ++m) {
      const float v = (&v0.x)[m];
      const _Float16 hv = (_Float16)v;
      h[m] = hv; l[m] = (_Float16)((v - (float)hv) * 2048.0f);
    }
#pragma unroll
    for (int m = 0; m < 4; ++m) {
      const float v = (&v1.x)[m];
      const _Float16 hv = (_Float16)v;
      h[m + 4] = hv; l[m + 4] = (_Float16)((v - (float)hv) * 2048.0f);
    }
    *(half8*)&xs[sx_off] = h;
    *(half8*)&xs[sx_off + 2048] = l;
  }
  half8 bh0 = *(const half8*)whg;
  half8 bl0 = *(const half8*)wlg;
  half8 bh1 = *(const half8*)(whg + 512);
  half8 bl1 = *(const half8*)(wlg + 512);

  for (int c = 0; c < NCH; ++c) {
    __syncthreads();                     // buf (c&1) visible; buf (c&1)^1 free
    half8 nbh0, nbl0, nbh1, nbl1; float4 npx0, npx1;
    if (c + 1 < NCH) {                   // prefetch next B (regs) + next x
      const _Float16* wp = whg + (size_t)(2 * (c + 1)) * 512;
      const _Float16* lp = wlg + (size_t)(2 * (c + 1)) * 512;
      nbh0 = *(const half8*)wp;  nbh1 = *(const half8*)(wp + 512);
      nbl0 = *(const half8*)lp;  nbl1 = *(const half8*)(lp + 512);
      if (xstage) {
        npx0 = *(const float4*)(xg + (c + 1) * KC);
        npx1 = *(const float4*)(xg + (c + 1) * KC + 4);
      }
    }
    const int bo = (c & 1) * 4096;
    const half8 a00 = *(const half8*)&xs[bo + offA00];
    const half8 l00 = *(const half8*)&xs[bo + offA00 + 2048];
    const half8 a01 = *(const half8*)&xs[bo + offA01];
    const half8 l01 = *(const half8*)&xs[bo + offA01 + 2048];
    const half8 a10 = *(const half8*)&xs[bo + offA10];
    const half8 l10 = *(const half8*)&xs[bo + offA10 + 2048];
    const half8 a11 = *(const half8*)&xs[bo + offA11];
    const half8 l11 = *(const half8*)&xs[bo + offA11 + 2048];

    // kstep 0
    hh0 = __builtin_amdgcn_mfma_f32_16x16x32_f16(a00, bh0, hh0, 0, 0, 0);
    cr0 = __builtin_amdgcn_mfma_f32_16x16x32_f16(a00, bl0, cr0, 0, 0, 0);
    cr0 = __builtin_amdgcn_mfma_f32_16x16x32_f16(l00, bh0, cr0, 0, 0, 0);
    hh1 = __builtin_amdgcn_mfma_f32_16x16x32_f16(a01, bh0, hh1, 0, 0, 0);
    cr1 = __builtin_amdgcn_mfma_f32_16x16x32_f16(a01, bl0, cr1, 0, 0, 0);
    cr1 = __builtin_amdgcn_mfma_f32_16x16x32_f16(l01, bh0, cr1, 0, 0, 0);
    // kstep 1
    hh0 = __builtin_amdgcn_mfma_f32_16x16x32_f16(a10, bh1, hh0, 0, 0, 0);
    cr0 = __builtin_amdgcn_mfma_f32_16x16x32_f16(a10, bl1, cr0, 0, 0, 0);
    cr0 = __builtin_amdgcn_mfma_f32_16x16x32_f16(l10, bh1, cr0, 0, 0, 0);
    hh1 = __builtin_amdgcn_mfma_f32_16x16x32_f16(a11, bh1, hh1, 0, 0, 0);
    cr1 = __builtin_amdgcn_mfma_f32_16x16x32_f16(a11, bl1, cr1, 0, 0, 0);
    cr1 = __builtin_amdgcn_mfma_f32_16x16x32_f16(l11, bh1, cr1, 0, 0, 0);

    if (c + 1 < NCH) {
      if (xstage) {                      // convert + write into the free buffer
        const int bn = ((c + 1) & 1) * 4096;
        half8 h, l;
#pragma unroll
        for (int m = 0; m < 4; ++m) {
          const float v = (&npx0.x)[m];
          const _Float16 hv = (_Float16)v;
          h[m] = hv; l[m] = (_Float16)((v - (float)hv) * 2048.0f);
        }
#pragma unroll
        for (int m = 0; m < 4; ++m) {
          const float v = (&npx1.x)[m];
          const _Float16 hv = (_Float16)v;
          h[m + 4] = hv; l[m + 4] = (_Float16)((v - (float)hv) * 2048.0f);
        }
        *(half8*)&xs[bn + sx_off] = h;
        *(half8*)&xs[bn + sx_off + 2048] = l;
      }
      bh0 = nbh0; bl0 = nbl0; bh1 = nbh1; bl1 = nbl1;
    }
  }
  __syncthreads();                       // GEMM LDS dead

  // ---- unscale, add rnn, write emb to A (C/D: col=lane&15, row=quad*4+r) ----
  {
    const int e  = nt * 16 + col;
    const float rv = rnn[e];
#pragma unroll
    for (int r = 0; r < 4; ++r) {
      A[swz(quad * 4 + r, e)] =
          hh0[r] * (1.0f / 32.0f) + cr0[r] * (1.0f / 65536.0f) + rv;
      A[swz(16 + quad * 4 + r, e)] =
          hh1[r] * (1.0f / 32.0f) + cr1[r] * (1.0f / 65536.0f) + rv;
    }
  }
  __syncthreads();

  // ---- LayerNorm + exact GELU: 4 tokens per wave; G -> G4 (float4-swizzled) ----
  {
    const float gm0 = gamma[lane], gm1 = gamma[lane + 64];
    const float bt0 = beta[lane],  bt1 = beta[lane + 64];
    for (int tt = wv * 4; tt < wv * 4 + 4; ++tt) {
      const float v0 = A[swz(tt, lane)];
      const float v1 = A[swz(tt, lane + 64)];
      float s = v0 + v1;
#pragma unroll
      for (int m = 32; m; m >>= 1) s += __shfl_xor(s, m);
      const float mu = s * (1.0f / 128.0f);
      const float d0 = v0 - mu, d1 = v1 - mu;
      float q = d0 * d0 + d1 * d1;
#pragma unroll
      for (int m = 32; m; m >>= 1) q += __shfl_xor(q, m);
      const float rstd = 1.0f / sqrtf(q * (1.0f / 128.0f) + 1e-5f);
      const float h0v = d0 * rstd * gm0 + bt0;
      const float h1v = d1 * rstd * gm1 + bt1;
      const float g0 = 0.5f * h0v * (1.0f + erff(h0v * 0.70710678118654752f));
      const float g1 = 0.5f * h1v * (1.0f + erff(h1v * 0.70710678118654752f));
      const int e0a = lane, e1a = lane + 64;
      G4[(tt * 32 + (((e0a >> 2) ^ (tt & 31)))) * 4 + (e0a & 3)] = g0;
      G4[(tt * 32 + (((e1a >> 2) ^ (tt & 31)))) * 4 + (e1a & 3)] = g1;
    }
  }
  __syncthreads();

  // ---- decoder GEMM: wave = 8 h-rows x 32 tokens, two h-halves ----
  {
    const int tok = lane & 31;
#pragma unroll
    for (int hb = 0; hb < 2; ++hb) {
      const int e0h = hb * 64 + wv * 8;
      float acc2[8];
#pragma unroll
      for (int j = 0; j < 8; ++j) acc2[j] = 0.0f;
      const float4* wd4 = (const float4*)(Wd + (size_t)e0h * EDIM);  // uniform
#pragma unroll 2
      for (int kg = 0; kg < EDIM / 4; ++kg) {
        const float4 gv = *(const float4*)&G4[(tok * 32 + (kg ^ tok)) * 4];
#pragma unroll
        for (int j = 0; j < 8; ++j) {
          const float4 w = wd4[(size_t)j * (EDIM / 4) + kg];
          acc2[j] = fmaf(gv.x, w.x,
                    fmaf(gv.y, w.y,
                    fmaf(gv.z, w.z,
                    fmaf(gv.w, w.w, acc2[j]))));
        }
      }
      if (lane < 32) {
#pragma unroll
        for (int j = 0; j < 8; ++j) A[swz(tok, e0h + j)] = acc2[j];
      }
    }
  }
  __syncthreads();

  // ---- gumbel-sigmoid, exact top-k (value then lower-index), output ----
  for (int tt = wv * 4; tt < wv * 4 + 4; ++tt) {
    const size_t T = (size_t)(t0 + tt);
    const float l0 = A[swz(tt, lane)];
    const float l1 = A[swz(tt, lane + 64)];
    const float gn0 = gum[T * HDIM + lane];
    const float gn1 = gum[T * HDIM + lane + 64];
    const float z0 = (l0 + gn0 + 3.0f) * 2.5f;
    const float z1 = (l1 + gn1 + 3.0f) * 2.5f;
    const float ba0 = 1.0f / (1.0f + expf(-z0));
    const float ba1 = 1.0f / (1.0f + expf(-z1));
    const unsigned ub0 = __float_as_uint(ba0);   // ba in (0,1]: bits monotone
    const unsigned ub1 = __float_as_uint(ba1);
    const int r0 = ba0 > 0.5f;                   // round: 0.5 -> 0
    const int r1 = ba1 > 0.5f;
    const int cnt = __popcll(__ballot(r0)) + __popcll(__ballot(r1));
    float bin0, bin1;
    if (cnt > 32) {
      unsigned v = 0u;                            // radix-select 32nd largest
#pragma unroll
      for (int b = 29; b >= 0; --b) {
        const unsigned cand = v | (1u << b);
        const int cc = __popcll(__ballot(ub0 >= cand)) + __popcll(__ballot(ub1 >= cand));
        if (cc >= 32) v = cand;
      }
      const int cgt = __popcll(__ballot(ub0 > v)) + __popcll(__ballot(ub1 > v));
      const int r = 32 - cgt;                     // tied slots; lower index wins
      const unsigned long long t0b = __ballot(ub0 == v);
      const unsigned long long t1b = __ballot(ub1 == v);
      const int n0 = __popcll(t0b);
      const unsigned long long mlt = (1ull << lane) - 1ull;
      const int rk0 = __popcll(t0b & mlt);
      const int rk1 = n0 + __popcll(t1b & mlt);
      bin0 = (ub0 > v || (ub0 == v && rk0 < r)) ? 1.0f : 0.0f;
      bin1 = (ub1 > v || (ub1 == v && rk1 < r)) ? 1.0f : 0.0f;
    } else if (cnt == 0) {
      float m = fmaxf(ba0, ba1);
#pragma unroll
      for (int mm = 32; mm; mm >>= 1) m = fmaxf(m, __shfl_xor(m, mm));
      const unsigned long long e0b = __ballot(ba0 == m);
      const unsigned long long e1b = __ballot(ba1 == m);
      const int hstar = e0b ? (__ffsll((unsigned long long)e0b) - 1)
                            : (64 + __ffsll((unsigned long long)e1b) - 1);
      bin0 = (lane == hstar) ? 1.0f : 0.0f;
      bin1 = (lane + 64 == hstar) ? 1.0f : 0.0f;
    } else {
      bin0 = r0 ? 1.0f : 0.0f;
      bin1 = r1 ? 1.0f : 0.0f;
    }
    outb[T * HDIM + lane]      = bin0;
    outb[T * HDIM + lane + 64] = bin1;
    outa[T * HDIM + lane]      = ba0;
    outa[T * HDIM + lane + 64] = ba1;
  }
}

extern "C" void kernel_launch(void* const* d_in, const int* in_sizes, int n_in,
                              void* d_out, int out_size, void* d_ws, size_t ws_size,
                              hipStream_t stream) {
  (void)in_sizes; (void)n_in; (void)ws_size; (void)out_size;
  const float* x   = (const float*)d_in[0];
  const float* Wr  = (const float*)d_in[1];
  const float* Wd  = (const float*)d_in[2];
  const float* gm  = (const float*)d_in[3];
  const float* bt  = (const float*)d_in[4];
  const float* rnn = (const float*)d_in[5];
  const float* gum = (const float*)d_in[6];
  float* outb = (float*)d_out;
  float* outa = outb + (size_t)NTOK * HDIM;   // tuple: (binary, binary_approx)

  _Float16* wh = (_Float16*)d_ws;             // 512 KB
  _Float16* wl = wh + (size_t)EDIM * DDIM;    // 512 KB

  conv_w<<<dim3(128), dim3(256), 0, stream>>>(Wr, wh, wl);
  fused_router<<<dim3(NTOK / TOKT), dim3(512), 0, stream>>>(
      x, wh, wl, Wd, gm, bt, rnn, gum, outb, outa);
}